// Round 1
// baseline (909.769 us; speedup 1.0000x reference)
//
#include <hip/hip_runtime.h>
#include <math.h>

#define MD 1024
#define NWG_ADAM 32
#define BLK 512
#define TOTAL_BLOCKS 256
#define B_BLOCKS (TOTAL_BLOCKS - NWG_ADAM)      // 224
#define WAVES_PER_BLOCK (BLK / 64)              // 8
#define B_WAVES (B_BLOCKS * WAVES_PER_BLOCK)    // 1792
#define BS_ROWS 65536

// workspace float-index layout
#define WS_AA_F 64      // aa[1024] at byte 256
#define WS_I1_F 1152    // 32 inter1 partials
#define WS_LS_F 1216    // 224 log-sigmoid partials

__device__ __forceinline__ void grid_barrier(unsigned* ctr, unsigned target) {
  __syncthreads();
  if (threadIdx.x == 0) {
    __threadfence();                 // release: drain stores, flush XCD L2 -> LLC
    atomicAdd(ctr, 1u);              // device-scope
    while (__hip_atomic_load(ctr, __ATOMIC_RELAXED, __HIP_MEMORY_SCOPE_AGENT) < target) { }
    __threadfence();                 // acquire: invalidate caches
  }
  __syncthreads();
}

__global__ __launch_bounds__(BLK, 2) void fused_kernel(
    const float* __restrict__ mean, const float* __restrict__ va,
    const float* __restrict__ xt, float* __restrict__ ws) {
  __shared__ float lds8[WAVES_PER_BLOCK];
  const int b = blockIdx.x;
  const int tid = (int)threadIdx.x;
  const int wv = tid >> 6;
  const int lane = tid & 63;
  unsigned* ctr = (unsigned*)ws;
  float* aa = ws + WS_AA_F;

  if (b < NWG_ADAM) {
    // ---------------- Adam persistent blocks ----------------
    const int rbase = b * 32 + wv * 4;     // this wave owns rows rbase..rbase+3
    float q[4][16];                        // Qsym fragments: row r, cols lane*16..+15

    // row part (coalesced)
#pragma unroll
    for (int r = 0; r < 4; ++r) {
      const float4* rp = (const float4*)(va + (size_t)(rbase + r) * MD + lane * 16);
      float4 v0 = rp[0], v1 = rp[1], v2 = rp[2], v3 = rp[3];
      q[r][0] = v0.x; q[r][1] = v0.y; q[r][2]  = v0.z; q[r][3]  = v0.w;
      q[r][4] = v1.x; q[r][5] = v1.y; q[r][6]  = v1.z; q[r][7]  = v1.w;
      q[r][8] = v2.x; q[r][9] = v2.y; q[r][10] = v2.z; q[r][11] = v2.w;
      q[r][12] = v3.x; q[r][13] = v3.y; q[r][14] = v3.z; q[r][15] = v3.w;
    }
    // transpose part: va[col][rbase..rbase+3] is a contiguous float4
#pragma unroll
    for (int k = 0; k < 16; ++k) {
      float4 cv = *(const float4*)(va + (size_t)(lane * 16 + k) * MD + rbase);
      q[0][k] = 0.5f * (q[0][k] + cv.x);
      q[1][k] = 0.5f * (q[1][k] + cv.y);
      q[2][k] = 0.5f * (q[2][k] + cv.z);
      q[3][k] = 0.5f * (q[3][k] + cv.w);
    }

    const bool owner = (lane < 4);
    const int myrow = rbase + (lane & 3);
    const float mmy = owner ? mean[myrow] : 0.f;
    float wcur = 1.f, mo = 0.f, vo = 0.f;

    if (owner) aa[myrow] = 1.f - mmy;      // aa_0 = w0 - mean
    unsigned gen = 1;
    grid_barrier(ctr, NWG_ADAM * gen); ++gen;

    float pb1 = 1.f, pb2 = 1.f;
    float p0, p1, p2, p3;

    for (int t = 1; t < 200; ++t) {
      const float4* ap = (const float4*)(aa + lane * 16);
      float4 a0 = ap[0], a1 = ap[1], a2 = ap[2], a3 = ap[3];
      float a[16];
      a[0] = a0.x; a[1] = a0.y; a[2]  = a0.z; a[3]  = a0.w;
      a[4] = a1.x; a[5] = a1.y; a[6]  = a1.z; a[7]  = a1.w;
      a[8] = a2.x; a[9] = a2.y; a[10] = a2.z; a[11] = a2.w;
      a[12] = a3.x; a[13] = a3.y; a[14] = a3.z; a[15] = a3.w;
      p0 = 0.f; p1 = 0.f; p2 = 0.f; p3 = 0.f;
#pragma unroll
      for (int k = 0; k < 16; ++k) {
        p0 = fmaf(q[0][k], a[k], p0);
        p1 = fmaf(q[1][k], a[k], p1);
        p2 = fmaf(q[2][k], a[k], p2);
        p3 = fmaf(q[3][k], a[k], p3);
      }
#pragma unroll
      for (int m = 1; m < 64; m <<= 1) {
        p0 += __shfl_xor(p0, m);
        p1 += __shfl_xor(p1, m);
        p2 += __shfl_xor(p2, m);
        p3 += __shfl_xor(p3, m);
      }
      pb1 *= 0.9f; pb2 *= 0.999f;
      if (owner) {
        float g = (lane == 0) ? p0 : (lane == 1) ? p1 : (lane == 2) ? p2 : p3;
        mo = 0.9f * mo + 0.1f * g;
        vo = 0.999f * vo + 0.001f * (g * g);
        float mhat = mo / (1.f - pb1);
        float vhat = vo / (1.f - pb2);
        wcur -= 0.1f * mhat / (sqrtf(vhat) + 1e-8f);
        aa[myrow] = wcur - mmy;
      }
      grid_barrier(ctr, NWG_ADAM * gen); ++gen;
    }

    // final inter1 partial: q = aa^T Qsym aa over owned rows
    {
      const float4* ap = (const float4*)(aa + lane * 16);
      float4 a0 = ap[0], a1 = ap[1], a2 = ap[2], a3 = ap[3];
      float a[16];
      a[0] = a0.x; a[1] = a0.y; a[2]  = a0.z; a[3]  = a0.w;
      a[4] = a1.x; a[5] = a1.y; a[6]  = a1.z; a[7]  = a1.w;
      a[8] = a2.x; a[9] = a2.y; a[10] = a2.z; a[11] = a2.w;
      a[12] = a3.x; a[13] = a3.y; a[14] = a3.z; a[15] = a3.w;
      p0 = 0.f; p1 = 0.f; p2 = 0.f; p3 = 0.f;
#pragma unroll
      for (int k = 0; k < 16; ++k) {
        p0 = fmaf(q[0][k], a[k], p0);
        p1 = fmaf(q[1][k], a[k], p1);
        p2 = fmaf(q[2][k], a[k], p2);
        p3 = fmaf(q[3][k], a[k], p3);
      }
#pragma unroll
      for (int m = 1; m < 64; m <<= 1) {
        p0 += __shfl_xor(p0, m);
        p1 += __shfl_xor(p1, m);
        p2 += __shfl_xor(p2, m);
        p3 += __shfl_xor(p3, m);
      }
      float contrib = 0.f;
      if (owner) {
        float y = (lane == 0) ? p0 : (lane == 1) ? p1 : (lane == 2) ? p2 : p3;
        contrib = (wcur - mmy) * y;
      }
#pragma unroll
      for (int m = 1; m < 64; m <<= 1) contrib += __shfl_xor(contrib, m);
      if (lane == 0) lds8[wv] = contrib;
      __syncthreads();
      if (tid == 0) {
        float s = 0.f;
#pragma unroll
        for (int i = 0; i < WAVES_PER_BLOCK; ++i) s += lds8[i];
        ws[WS_I1_F + b] = s;
      }
    }
  } else {
    // ---------------- log-sigmoid streaming blocks ----------------
    const int gw = (b - NWG_ADAM) * WAVES_PER_BLOCK + wv;
    const float4* mp = (const float4*)mean;
    float4 m0 = mp[0 * 64 + lane];
    float4 m1 = mp[1 * 64 + lane];
    float4 m2 = mp[2 * 64 + lane];
    float4 m3 = mp[3 * 64 + lane];
    float lsum = 0.f;
    for (int row = gw; row < BS_ROWS; row += B_WAVES) {
      const float4* xr = (const float4*)(xt + (size_t)row * MD);
      float4 x0 = xr[0 * 64 + lane];
      float4 x1 = xr[1 * 64 + lane];
      float4 x2 = xr[2 * 64 + lane];
      float4 x3 = xr[3 * 64 + lane];
      float acc = 0.f;
      acc = fmaf(x0.x, m0.x, acc); acc = fmaf(x0.y, m0.y, acc);
      acc = fmaf(x0.z, m0.z, acc); acc = fmaf(x0.w, m0.w, acc);
      acc = fmaf(x1.x, m1.x, acc); acc = fmaf(x1.y, m1.y, acc);
      acc = fmaf(x1.z, m1.z, acc); acc = fmaf(x1.w, m1.w, acc);
      acc = fmaf(x2.x, m2.x, acc); acc = fmaf(x2.y, m2.y, acc);
      acc = fmaf(x2.z, m2.z, acc); acc = fmaf(x2.w, m2.w, acc);
      acc = fmaf(x3.x, m3.x, acc); acc = fmaf(x3.y, m3.y, acc);
      acc = fmaf(x3.z, m3.z, acc); acc = fmaf(x3.w, m3.w, acc);
#pragma unroll
      for (int m = 1; m < 64; m <<= 1) acc += __shfl_xor(acc, m);
      if (lane == 0) {
        float z = fminf(acc, 0.f);
        lsum += z - log1pf(expf(-fabsf(acc)));
      }
    }
    if (lane == 0) lds8[wv] = lsum;
    __syncthreads();
    if (tid == 0) {
      float s = 0.f;
#pragma unroll
      for (int i = 0; i < WAVES_PER_BLOCK; ++i) s += lds8[i];
      ws[WS_LS_F + (b - NWG_ADAM)] = s;
    }
  }
}

__global__ void finalize_kernel(const float* __restrict__ ws, float* __restrict__ out) {
  const int lane = (int)threadIdx.x & 63;
  float qsum = (lane < NWG_ADAM) ? ws[WS_I1_F + lane] : 0.f;
  float lssum = 0.f;
  for (int i = lane; i < B_BLOCKS; i += 64) lssum += ws[WS_LS_F + i];
#pragma unroll
  for (int m = 1; m < 64; m <<= 1) {
    qsum += __shfl_xor(qsum, m);
    lssum += __shfl_xor(lssum, m);
  }
  if (lane == 0) out[0] = 0.5f * qsum - lssum;
}

extern "C" void kernel_launch(void* const* d_in, const int* in_sizes, int n_in,
                              void* d_out, int out_size, void* d_ws, size_t ws_size,
                              hipStream_t stream) {
  (void)in_sizes; (void)n_in; (void)out_size; (void)ws_size;
  const float* mean = (const float*)d_in[0];
  const float* va   = (const float*)d_in[1];
  const float* xt   = (const float*)d_in[2];
  float* out = (float*)d_out;
  float* ws  = (float*)d_ws;

  // reset the grid-barrier counter region only (bytes [0,256))
  hipMemsetAsync(d_ws, 0, 256, stream);
  fused_kernel<<<TOTAL_BLOCKS, BLK, 0, stream>>>(mean, va, xt, ws);
  finalize_kernel<<<1, 64, 0, stream>>>(ws, out);
}